// Round 18
// baseline (144.168 us; speedup 1.0000x reference)
//

#include <hip/hip_runtime.h>

// RadiusInteractionGraph: B=128 molecules x 512 atoms, K=32 NN, cutoff 10.
// d_out is FLOAT32: [E] src ++ [E] dst ++ [E] weight, E = 128*512*32.
//
// R18: R15 structure (PASS @ 88us, issue-bound) with a cheaper wave-min:
//  - levels 1-4: DPP permutation patterns with no old-value init
//    (quad_perm xor1/xor2, row_half_mirror, row_mirror) — 1 dpp-mov + 1 min
//    each, foldable to v_min_u32_dpp;
//  - levels 5-6: __shfl_xor(16/32) — LDS pipe, off the VALU bottleneck;
//  - all lanes end with the min in a VGPR: no readlane, VGPR-VGPR compares.
//  - sort-8 compare-exchange via min/max (2 VALU) instead of min+xor+xor (3).
//  - dual-row interleave dropped (R17 proved zero gain at 98% VALUBusy).
// Selection semantics identical: key = (d2_hi23 | j) lexicographic ==
// lax.top_k stable order; exact __f*_rn np arithmetic (no FMA contraction).

constexpr int EDGES = 128 * 512 * 32;   // 2097152

static __device__ __forceinline__ unsigned umin2(unsigned a, unsigned b) {
    return a < b ? a : b;
}
static __device__ __forceinline__ unsigned umax2(unsigned a, unsigned b) {
    return a > b ? a : b;
}

template <int CTRL>
static __device__ __forceinline__ unsigned dpp_perm_min(unsigned x) {
    // Pure permutation patterns (always-valid lanes, full masks): old value
    // never consumed -> pass x itself; no init-mov needed.
    int t = __builtin_amdgcn_update_dpp((int)x, (int)x, CTRL, 0xF, 0xF, false);
    return umin2((unsigned)t, x);
}

// All-lanes wave64 min: 4 DPP butterfly levels + 2 LDS-pipe shuffle levels.
static __device__ __forceinline__ unsigned wave_min64_all(unsigned x) {
    x = dpp_perm_min<0xB1>(x);    // quad_perm(1,0,3,2)  : xor 1
    x = dpp_perm_min<0x4E>(x);    // quad_perm(2,3,0,1)  : xor 2
    x = dpp_perm_min<0x141>(x);   // row_half_mirror     : pairs quads in 8
    x = dpp_perm_min<0x140>(x);   // row_mirror          : pairs 8s in 16
    x = umin2(x, (unsigned)__shfl_xor((int)x, 16, 64));   // LDS pipe
    x = umin2(x, (unsigned)__shfl_xor((int)x, 32, 64));   // LDS pipe
    return x;                     // every lane holds the global min
}

__global__ __launch_bounds__(256)
void RadiusInteractionGraph_73246372266582_kernel(const float* __restrict__ pos,
                                                  float* __restrict__ out) {
    __shared__ float4 atoms[512];     // x, y, z, |p|^2

    const int tid     = threadIdx.x;
    const int b       = blockIdx.x >> 5;          // 32 blocks per molecule
    const int rowbase = (blockIdx.x & 31) * 16;   // 16 rows per block
    const int base    = b * 512;

    for (int a = tid; a < 512; a += 256) {
        float x = pos[(base + a) * 3 + 0];
        float y = pos[(base + a) * 3 + 1];
        float z = pos[(base + a) * 3 + 2];
        // np: sum(p*p) = (x*x + y*y) + z*z, sequential f32, no fma
        float sq = __fadd_rn(__fadd_rn(__fmul_rn(x, x), __fmul_rn(y, y)),
                             __fmul_rn(z, z));
        atoms[a] = make_float4(x, y, z, sq);
    }
    __syncthreads();

    const int wave = tid >> 6;
    const int lane = tid & 63;

    for (int rr = 0; rr < 4; ++rr) {
        const int i = rowbase + wave * 4 + rr;    // this wave's center row
        const float4 ci = atoms[i];               // uniform addr -> broadcast

        // ---- build 8 candidate keys per lane (j = c*64 + lane) ----
        unsigned q[8];
#pragma unroll
        for (int c = 0; c < 8; ++c) {
            const int j = c * 64 + lane;
            const float4 pj = atoms[j];           // one ds_read_b128
            // np einsum order: ((xi*xj + yi*yj) + zi*zj), plain f32, no fma
            float dot = __fadd_rn(__fadd_rn(__fmul_rn(ci.x, pj.x),
                                            __fmul_rn(ci.y, pj.y)),
                                  __fmul_rn(ci.z, pj.z));
            float d2 = __fsub_rn(__fadd_rn(ci.w, pj.w), __fmul_rn(2.0f, dot));
            d2 = fmaxf(d2, 0.0f);
            q[c] = ((j != i) && (d2 <= 100.0f))
                       ? ((__float_as_uint(d2) & 0xFFFFFE00u) | (unsigned)j)
                       : 0xFFFFFFFFu;
        }

        // ---- per-lane sort-8 ascending (Batcher, 19 CE x 2 VALU) ----
#define CE(a_, b_) { unsigned lo = umin2(q[a_], q[b_]); \
                     unsigned hi = umax2(q[a_], q[b_]); \
                     q[a_] = lo; q[b_] = hi; }
        CE(0,1) CE(2,3) CE(4,5) CE(6,7)
        CE(0,2) CE(1,3) CE(4,6) CE(5,7)
        CE(1,2) CE(5,6)
        CE(0,4) CE(1,5) CE(2,6) CE(3,7)
        CE(2,4) CE(3,5)
        CE(1,2) CE(3,4) CE(5,6)
#undef CE

        // ---- 32 extraction rounds; lane r captures the r-th smallest ----
        unsigned res = 0xFFFFFFFFu;
#pragma unroll
        for (int r = 0; r < 32; ++r) {
            const unsigned m = wave_min64_all(q[0]);  // VGPR, wave-uniform
            res = (lane == r) ? m : res;
            const bool adv = (q[0] == m);             // unique -> one winner
            q[0] = adv ? q[1] : q[0];
            q[1] = adv ? q[2] : q[1];
            q[2] = adv ? q[3] : q[2];
            q[3] = adv ? q[4] : q[3];
            q[4] = adv ? q[5] : q[4];
            q[5] = adv ? q[6] : q[5];
            q[6] = adv ? q[7] : q[6];
            q[7] = adv ? 0xFFFFFFFFu : q[7];
        }

        // ---- epilogue: lanes 0..31 -> coalesced 128 B stores per region ----
        if (lane < 32) {
            const int gdst = base + i;
            float w = 0.0f;
            float srcf = (float)gdst;             // pad = self-edge, weight 0
            if (res != 0xFFFFFFFFu) {
                const int j = (int)(res & 511u);
                const float4 pj = atoms[j];
                float dot = __fadd_rn(__fadd_rn(__fmul_rn(ci.x, pj.x),
                                                __fmul_rn(ci.y, pj.y)),
                                      __fmul_rn(ci.z, pj.z));
                float d2 = __fsub_rn(__fadd_rn(ci.w, pj.w),
                                     __fmul_rn(2.0f, dot));
                d2 = fmaxf(d2, 0.0f);
                w = __fsqrt_rn(fmaxf(d2, 1e-12f));
                srcf = (float)(base + j);
            }
            const size_t eb = (size_t)gdst * 32 + (size_t)lane;
            out[eb]                     = srcf;          // src
            out[(size_t)EDGES + eb]     = (float)gdst;   // dst
            out[(size_t)EDGES * 2 + eb] = w;             // weight
        }
    }
}

extern "C" void kernel_launch(void* const* d_in, const int* in_sizes, int n_in,
                              void* d_out, int out_size, void* d_ws, size_t ws_size,
                              hipStream_t stream) {
    (void)in_sizes; (void)n_in; (void)d_ws; (void)ws_size; (void)out_size;
    const float* pos = (const float*)d_in[0];   // [N,3] f32
    float* out       = (float*)d_out;           // [3E] f32

    RadiusInteractionGraph_73246372266582_kernel<<<dim3(4096), dim3(256), 0,
                                                   stream>>>(pos, out);
}
